// Round 5
// baseline (1083.502 us; speedup 1.0000x reference)
//
#include <hip/hip_runtime.h>

// ---------------------------------------------------------------------------
// SubAttention fused pipeline for MI355X (gfx950). f32 I/O, bf16 MFMA compute.
// B=8 T=2048 Tc=512 D=1024 Dc=512 H=8 hd=128 N=2560
// ---------------------------------------------------------------------------

typedef short s16x8 __attribute__((ext_vector_type(8)));
typedef float f32x4 __attribute__((ext_vector_type(4)));

__device__ __forceinline__ float b2f(short s) {
    unsigned int u = ((unsigned int)(unsigned short)s) << 16;
    return __uint_as_float(u);
}
__device__ __forceinline__ short f2b(float f) {
    unsigned int u = __float_as_uint(f);
    u += 0x7fffu + ((u >> 16) & 1u);   // round-to-nearest-even
    return (short)(u >> 16);
}

typedef void __attribute__((address_space(1)))* gas_ptr;
typedef void __attribute__((address_space(3)))* las_ptr;
__device__ __forceinline__ void async_cp16(const void* g, void* l) {
    __builtin_amdgcn_global_load_lds((gas_ptr)g, (las_ptr)l, 16, 0, 0);
}

__device__ __forceinline__ float pen_of(const float* __restrict__ cmask,
                                        const float* __restrict__ smask,
                                        int b, int n) {
    float mk = (n < 512) ? cmask[b * 512 + n] : smask[b * 2048 + n - 512];
    return (1.0f - mk) * -1000000.0f;
}

// XCD-aware bijective block remap: keeps panel-sharing groups on one XCD's L2.
// Requires (gridDim.y*gridDim.z) % 8 == 0 (all our grids comply).
__device__ __forceinline__ void xcd_remap(int& gx, int& gy, int& gz) {
    int lb = blockIdx.x + gridDim.x * (blockIdx.y + gridDim.y * blockIdx.z);
    int nx = gridDim.x;
    int gpx = (gridDim.y * gridDim.z) >> 3;
    int xcd = lb & 7, rest = lb >> 3;
    gx = rest % nx;
    int gidx = xcd * gpx + rest / nx;
    gy = gidx % gridDim.y;
    gz = gidx / gridDim.y;
}

// ---------------------------------------------------------------------------
// One-shot f32->bf16 weight conversion into the contiguous ws weight region:
// [wkc 512K][wvc 512K][wkx 1M][wvx 1M][wy 1M] elements.
__global__ __launch_bounds__(256) void cvt_all(const float* __restrict__ Wkc,
                                               const float* __restrict__ Wvc,
                                               const float* __restrict__ Wkx,
                                               const float* __restrict__ Wvx,
                                               const float* __restrict__ Wy,
                                               short* __restrict__ dst) {
    int g = (blockIdx.x * 256 + threadIdx.x) * 4;     // 0 .. 4194300
    const float* src;
    if (g < 524288)        src = Wkc + g;
    else if (g < 1048576)  src = Wvc + (g - 524288);
    else if (g < 2097152)  src = Wkx + (g - 1048576);
    else if (g < 3145728)  src = Wvx + (g - 2097152);
    else                   src = Wy  + (g - 3145728);
    float4 v = *(const float4*)src;
    short4 o;
    o.x = f2b(v.x); o.y = f2b(v.y); o.z = f2b(v.z); o.w = f2b(v.w);
    *(short4*)&dst[g] = o;
}

// ---------------------------------------------------------------------------
// LayerNorm: one row (length L = 1024 or 512) per block of 256 threads.
__global__ __launch_bounds__(256) void ln_kernel(const float* __restrict__ x,
                                                 const float* __restrict__ g,
                                                 const float* __restrict__ be,
                                                 short* __restrict__ out, int L) {
    long row = blockIdx.x;
    const float* xr = x + row * L;
    short* orow = out + row * L;
    int tid = threadIdx.x;
    int i0 = tid * 4;
    bool active = i0 < L;
    float v0 = 0.f, v1 = 0.f, v2 = 0.f, v3 = 0.f;
    if (active) {
        float4 p = *(const float4*)&xr[i0];
        v0 = p.x; v1 = p.y; v2 = p.z; v3 = p.w;
    }
    float s = v0 + v1 + v2 + v3;
    float s2 = v0*v0 + v1*v1 + v2*v2 + v3*v3;
    #pragma unroll
    for (int off = 32; off > 0; off >>= 1) {
        s  += __shfl_down(s, off);
        s2 += __shfl_down(s2, off);
    }
    __shared__ float ss[4], sq[4];
    int wave = tid >> 6, lane = tid & 63;
    if (lane == 0) { ss[wave] = s; sq[wave] = s2; }
    __syncthreads();
    if (tid == 0) {
        float t1 = ss[0] + ss[1] + ss[2] + ss[3];
        float t2 = sq[0] + sq[1] + sq[2] + sq[3];
        float mu = t1 / (float)L;
        float var = t2 / (float)L - mu * mu;
        ss[0] = mu;
        sq[0] = rsqrtf(var + 1e-5f);
    }
    __syncthreads();
    float mu = ss[0], rs = sq[0];
    if (active) {
        float4 gp = *(const float4*)&g[i0];
        float4 bp = *(const float4*)&be[i0];
        short4 o;
        o.x = f2b((v0 - mu) * rs * gp.x + bp.x);
        o.y = f2b((v1 - mu) * rs * gp.y + bp.y);
        o.z = f2b((v2 - mu) * rs * gp.z + bp.z);
        o.w = f2b((v3 - mu) * rs * gp.w + bp.w);
        *(short4*)&orow[i0] = o;
    }
}

// ---------------------------------------------------------------------------
// q softmax over last axis (rows of 128 f32). 4 rows per block (1 wave each).
__global__ __launch_bounds__(256) void qsoftmax_kernel(const float* __restrict__ q,
                                                       short* __restrict__ out) {
    long row = (long)blockIdx.x * 4 + (threadIdx.x >> 6);
    int lane = threadIdx.x & 63;
    const float* qr = q + row * 128;
    float2 p = *(const float2*)&qr[lane * 2];
    float v0 = p.x, v1 = p.y;
    float m = fmaxf(v0, v1);
    #pragma unroll
    for (int off = 32; off > 0; off >>= 1) m = fmaxf(m, __shfl_xor(m, off));
    float e0 = __expf(v0 - m), e1 = __expf(v1 - m);
    float s = e0 + e1;
    #pragma unroll
    for (int off = 32; off > 0; off >>= 1) s += __shfl_xor(s, off);
    float inv = 1.0f / s;
    short2 o; o.x = f2b(e0 * inv); o.y = f2b(e1 * inv);
    *(short2*)&out[row * 128 + lane * 2] = o;
}

// ---------------------------------------------------------------------------
// Column-softmax stats over n (N=2560), coalesced: one channel per thread.
__global__ __launch_bounds__(256) void kstats1(const short* __restrict__ klog,
                                               const float* __restrict__ cmask,
                                               const float* __restrict__ smask,
                                               float* __restrict__ partM,
                                               float* __restrict__ partS) {
    int c = blockIdx.x * 256 + threadIdx.x;
    int b = blockIdx.y;
    int n0 = blockIdx.z * 256;
    const short* base = klog + (long)b * 2560 * 1024 + c;
    float m = -3.4e38f, s = 0.f;
    for (int k = 0; k < 256; ++k) {
        int n = n0 + k;
        float v = b2f(base[(long)n * 1024]) + pen_of(cmask, smask, b, n);
        float nm = fmaxf(m, v);
        s = s * __expf(m - nm) + __expf(v - nm);
        m = nm;
    }
    long o = ((long)(b * 10 + blockIdx.z)) * 1024 + c;
    partM[o] = m;
    partS[o] = s;
}

__global__ __launch_bounds__(256) void kstats2(const float* __restrict__ partM,
                                               const float* __restrict__ partS,
                                               float* __restrict__ Ms,
                                               float* __restrict__ iSs) {
    int c = blockIdx.x * 256 + threadIdx.x;
    int b = blockIdx.y;
    float M = -3.4e38f;
    #pragma unroll
    for (int k = 0; k < 10; ++k)
        M = fmaxf(M, partM[((long)(b * 10 + k)) * 1024 + c]);
    float S = 0.f;
    #pragma unroll
    for (int k = 0; k < 10; ++k) {
        long o = ((long)(b * 10 + k)) * 1024 + c;
        S += partS[o] * __expf(partM[o] - M);
    }
    Ms[b * 1024 + c] = M;
    iSs[b * 1024 + c] = 1.0f / S;
}

// ---------------------------------------------------------------------------
// 128x128-tile bf16 MFMA B^T GEMM. BK=32, 4-buffer LDS ring (64 KiB),
// counted-vmcnt depth-3 prefetch, ONE barrier per K-tile. Verified R2-R4.
// MODE 0 (KV) : dual output. n<1024: OutA = bf16(acc + biasK[n]);
//               n>=1024: OutB = bf16((acc + biasV[n-1024]) * mask[row]).
// MODE 2 (ZT) : z=(b,h); OutA[b][row][h*128+n] = bf16(acc)
// MODE 4 (OUT): f32 OutA = acc + biasK[n], batched over z
template<int MODE>
__global__ __launch_bounds__(256) void gemm_bt(
        const short* __restrict__ A, int lda, long strideA,
        const short* __restrict__ B, int ldb,
        void* __restrict__ OutA, void* __restrict__ OutB,
        int ldo, long strideO,
        int K,
        const float* __restrict__ biasK, const float* __restrict__ biasV,
        const float* __restrict__ mask, long strideMask) {
    __shared__ short lds[4 * 8192];           // 4 bufs x 16 KiB
    int tid = threadIdx.x;
    int wave = tid >> 6, lane = tid & 63;
    int bx, by, bz;
    xcd_remap(bx, by, bz);
    int n0 = bx * 128;
    int m0 = by * 128;
    int z = bz;

    const short* Ab;
    const short* Bb;
    if (MODE == 2) {
        Ab = A + (z & 7) * 128;             // Wy columns h*128..h*128+127
        Bb = B + (long)z * 16384;           // attnD[z] (128 x 128)
    } else if (MODE == 4) {
        Ab = A + (long)z * strideA;         // qsm[b]
        Bb = B + (long)z * 1048576;         // Zt[b]
    } else {
        Ab = A + (long)z * strideA;
        Bb = B;                             // concatenated weights, shared
    }

    f32x4 acc[4][4];
    #pragma unroll
    for (int i = 0; i < 4; ++i)
        #pragma unroll
        for (int j = 0; j < 4; ++j) {
            f32x4 zz = {0.f, 0.f, 0.f, 0.f};
            acc[i][j] = zz;
        }

    int wm = wave >> 1, wn = wave & 1;
    int r = lane & 15, q = lane >> 4;

    // Per-thread staging: 4 chunks (it 0,1 -> A; 2,3 -> B), 1024 chunks total.
    const short* sp0; const short* sp1; const short* sp2; const short* sp3;
    int lo0, lo1, lo2, lo3;
    {
        #pragma unroll
        for (int it = 0; it < 4; ++it) {
            int cid = it * 256 + tid;          // 0..1023
            int rid = cid & 511;
            int srow = rid >> 3;               // 0..63
            int scol = rid & 7;
            int scol0 = scol ^ (srow & 7);
            int row = srow * 2 + (scol0 >> 2);
            int col = (scol0 & 3) << 3;
            const short* p = (cid < 512)
                ? (Ab + (long)(m0 + row) * lda + col)
                : (Bb + (long)(n0 + row) * ldb + col);
            int lo = cid * 8;
            if (it == 0) { sp0 = p; lo0 = lo; }
            else if (it == 1) { sp1 = p; lo1 = lo; }
            else if (it == 2) { sp2 = p; lo2 = lo; }
            else { sp3 = p; lo3 = lo; }
        }
    }

    // Fragment LDS offsets (shorts). A region [0,4096), B region [4096,8192).
    int offA[4], offB[4];
    #pragma unroll
    for (int i = 0; i < 4; ++i) {
        int rowA = wm * 64 + i * 16 + r;
        int srow = rowA >> 1;
        int slot = ((((rowA & 1) << 2) | q) ^ (srow & 7));
        offA[i] = srow * 64 + slot * 8;
        int rowB = wn * 64 + i * 16 + r;
        int srowB = rowB >> 1;
        int slotB = ((((rowB & 1) << 2) | q) ^ (srowB & 7));
        offB[i] = 4096 + srowB * 64 + slotB * 8;
    }

    int nt = K >> 5;                           // K-tiles of 32 (K>=128 -> nt>=4)
    // Prologue: stage tiles 0,1,2 into bufs 0,1,2.
    #pragma unroll
    for (int pt = 0; pt < 3; ++pt) {
        async_cp16(sp0 + (pt << 5), &lds[pt * 8192 + lo0]);
        async_cp16(sp1 + (pt << 5), &lds[pt * 8192 + lo1]);
        async_cp16(sp2 + (pt << 5), &lds[pt * 8192 + lo2]);
        async_cp16(sp3 + (pt << 5), &lds[pt * 8192 + lo3]);
    }

    for (int t = 0; t < nt; ++t) {
        if (t + 2 < nt)
            asm volatile("s_waitcnt vmcnt(8)\n\ts_barrier" ::: "memory");
        else if (t + 1 < nt)
            asm volatile("s_waitcnt vmcnt(4)\n\ts_barrier" ::: "memory");
        else
            asm volatile("s_waitcnt vmcnt(0)\n\ts_barrier" ::: "memory");
        const short* base = &lds[(t & 3) * 8192];
        s16x8 af[4], bfr[4];
        #pragma unroll
        for (int j = 0; j < 4; ++j) bfr[j] = *(const s16x8*)&base[offB[j]];
        #pragma unroll
        for (int i = 0; i < 4; ++i) af[i] = *(const s16x8*)&base[offA[i]];
        if (t + 3 < nt) {
            int buf = (t + 3) & 3;
            int ks = (t + 3) << 5;
            async_cp16(sp0 + ks, &lds[buf * 8192 + lo0]);
            async_cp16(sp1 + ks, &lds[buf * 8192 + lo1]);
            async_cp16(sp2 + ks, &lds[buf * 8192 + lo2]);
            async_cp16(sp3 + ks, &lds[buf * 8192 + lo3]);
        }
        __builtin_amdgcn_s_setprio(1);
        #pragma unroll
        for (int i = 0; i < 4; ++i)
            #pragma unroll
            for (int j = 0; j < 4; ++j)
                acc[i][j] = __builtin_amdgcn_mfma_f32_16x16x32_bf16(af[i], bfr[j], acc[i][j], 0, 0, 0);
        __builtin_amdgcn_s_setprio(0);
    }

    // Epilogue: C/D layout col = lane&15, row = (lane>>4)*4 + reg  [m89/m91]
    #pragma unroll
    for (int i = 0; i < 4; ++i) {
        int gmb = m0 + wm * 64 + i * 16 + q * 4;
        #pragma unroll
        for (int j = 0; j < 4; ++j) {
            int gn = n0 + wn * 64 + j * 16 + r;
            #pragma unroll
            for (int rg = 0; rg < 4; ++rg) {
                int row = gmb + rg;
                float v = acc[i][j][rg];
                if (MODE == 0) {
                    if (gn < 1024) {
                        ((short*)OutA)[(long)z * strideO + (long)row * ldo + gn] =
                            f2b(v + biasK[gn]);
                    } else {
                        int gv = gn - 1024;
                        float mk = mask[(long)z * strideMask + row];
                        ((short*)OutB)[(long)z * strideO + (long)row * ldo + gv] =
                            f2b((v + biasV[gv]) * mk);
                    }
                } else if (MODE == 2) {
                    ((short*)OutA)[(long)(z >> 3) * 1048576 + (long)row * 1024 +
                                   (z & 7) * 128 + gn] = f2b(v);
                } else {
                    ((float*)OutA)[(long)z * strideO + (long)row * ldo + gn] =
                        v + biasK[gn];
                }
            }
        }
    }
}

// ---------------------------------------------------------------------------
// 256x256-tile, 8-wave, BK=32 4-buffer ring (128 KiB dynamic, 1 block/CU).
// Verified best-per-block pipeline (R2). Used for OUT (grid 256 = 1/CU).
// MODE 0 (KV) : dual output, same semantics as gemm_bt<0>.
// MODE 4 (OUT): f32 OutA = acc + biasK[n], B batched per z (stride 1M elems).
template<int MODE>
__global__ __launch_bounds__(512, 2) void gemm256(
        const short* __restrict__ A, int lda, long strideA,
        const short* __restrict__ B, int ldb,
        void* __restrict__ OutA, void* __restrict__ OutB,
        int ldo, long strideO,
        int K,
        const float* __restrict__ biasK, const float* __restrict__ biasV,
        const float* __restrict__ mask, long strideMask) {
    extern __shared__ short lds[];            // 4 bufs x 16384 shorts
    int tid = threadIdx.x;
    int wave = tid >> 6, lane = tid & 63;
    int bx, by, bz;
    xcd_remap(bx, by, bz);
    int n0 = bx * 256;
    int m0 = by * 256;
    int z = bz;

    const short* Ab;
    const short* Bb;
    if (MODE == 4) {
        Ab = A + (long)z * strideA;           // qsm[b]
        Bb = B + (long)z * 1048576;           // Zt[b]
    } else {
        Ab = A + (long)z * strideA;
        Bb = B;                               // concatenated weights, shared
    }

    f32x4 acc[8][4];
    #pragma unroll
    for (int i = 0; i < 8; ++i)
        #pragma unroll
        for (int j = 0; j < 4; ++j) {
            f32x4 zz = {0.f, 0.f, 0.f, 0.f};
            acc[i][j] = zz;
        }

    int wm = wave >> 2, wn = wave & 3;        // 2 x 4 wave grid
    int r = lane & 15, q = lane >> 4;

    const short* sp0; const short* sp1; const short* sp2; const short* sp3;
    int lo0, lo1, lo2, lo3;
    {
        #pragma unroll
        for (int it = 0; it < 4; ++it) {
            int cid = it * 512 + tid;          // 0..2047
            int rid = cid & 1023;
            int srow = rid >> 3;               // 0..127
            int scol = rid & 7;
            int scol0 = scol ^ (srow & 7);
            int row = srow * 2 + (scol0 >> 2);
            int col = (scol0 & 3) << 3;
            const short* p = (cid < 1024)
                ? (Ab + (long)(m0 + row) * lda + col)
                : (Bb + (long)(n0 + row) * ldb + col);
            int lo = cid * 8;
            if (it == 0) { sp0 = p; lo0 = lo; }
            else if (it == 1) { sp1 = p; lo1 = lo; }
            else if (it == 2) { sp2 = p; lo2 = lo; }
            else { sp3 = p; lo3 = lo; }
        }
    }

    int offA[8], offB[4];
    #pragma unroll
    for (int i = 0; i < 8; ++i) {
        int rowA = wm * 128 + i * 16 + r;
        int srow = rowA >> 1;
        int slot = ((((rowA & 1) << 2) | q) ^ (srow & 7));
        offA[i] = srow * 64 + slot * 8;
    }
    #pragma unroll
    for (int j = 0; j < 4; ++j) {
        int rowB = wn * 64 + j * 16 + r;
        int srow = rowB >> 1;
        int slot = ((((rowB & 1) << 2) | q) ^ (srow & 7));
        offB[j] = 8192 + srow * 64 + slot * 8;
    }

    int nt = K >> 5;                           // K>=512 here -> nt>=16
    #pragma unroll
    for (int pt = 0; pt < 3; ++pt) {
        async_cp16(sp0 + (pt << 5), &lds[pt * 16384 + lo0]);
        async_cp16(sp1 + (pt << 5), &lds[pt * 16384 + lo1]);
        async_cp16(sp2 + (pt << 5), &lds[pt * 16384 + lo2]);
        async_cp16(sp3 + (pt << 5), &lds[pt * 16384 + lo3]);
    }

    for (int t = 0; t < nt; ++t) {
        if (t + 2 < nt)
            asm volatile("s_waitcnt vmcnt(8)\n\ts_barrier" ::: "memory");
        else if (t + 1 < nt)
            asm volatile("s_waitcnt vmcnt(4)\n\ts_barrier" ::: "memory");
        else
            asm volatile("s_waitcnt vmcnt(0)\n\ts_barrier" ::: "memory");
        const short* base = &lds[(t & 3) * 16384];
        s16x8 af[8], bfr[4];
        #pragma unroll
        for (int j = 0; j < 4; ++j) bfr[j] = *(const s16x8*)&base[offB[j]];
        #pragma unroll
        for (int i = 0; i < 8; ++i) af[i] = *(const s16x8*)&base[offA[i]];
        if (t + 3 < nt) {
            int buf = (t + 3) & 3;
            int ks = (t + 3) << 5;
            async_cp16(sp0 + ks, &lds[buf * 16384 + lo0]);
            async_cp16(sp1 + ks, &lds[buf * 16384 + lo1]);
            async_cp16(sp2 + ks, &lds[buf * 16384 + lo2]);
            async_cp16(sp3 + ks, &lds[buf * 16384 + lo3]);
        }
        __builtin_amdgcn_s_setprio(1);
        #pragma unroll
        for (int i = 0; i < 8; ++i)
            #pragma unroll
            for (int j = 0; j < 4; ++j)
                acc[i][j] = __builtin_amdgcn_mfma_f32_16x16x32_bf16(af[i], bfr[j], acc[i][j], 0, 0, 0);
        __builtin_amdgcn_s_setprio(0);
    }

    #pragma unroll
    for (int i = 0; i < 8; ++i) {
        int gmb = m0 + wm * 128 + i * 16 + q * 4;
        #pragma unroll
        for (int j = 0; j < 4; ++j) {
            int gn = n0 + wn * 64 + j * 16 + r;
            #pragma unroll
            for (int rg = 0; rg < 4; ++rg) {
                int row = gmb + rg;
                float v = acc[i][j][rg];
                if (MODE == 0) {
                    if (gn < 1024) {
                        ((short*)OutA)[(long)z * strideO + (long)row * ldo + gn] =
                            f2b(v + biasK[gn]);
                    } else {
                        int gv = gn - 1024;
                        float mk = mask[(long)z * strideMask + row];
                        ((short*)OutB)[(long)z * strideO + (long)row * ldo + gv] =
                            f2b((v + biasV[gv]) * mk);
                    }
                } else {
                    ((float*)OutA)[(long)z * strideO + (long)row * ldo + gn] =
                        v + biasK[gn];
                }
            }
        }
    }
}

// ---------------------------------------------------------------------------
// 256x256-tile, 8-wave, BK=32, TWO-buffer (64 KiB static -> 2 blocks/CU)
// counted-vmcnt GEMM. Combines the 256^2 compute/byte ratio with cross-block
// TLP (m114): while one block drains its stage, the co-resident block's MFMA
// keeps the CU busy. Schedule per K-tile t (buf = t&1):
//   [vmcnt(4); s_barrier]   <- stage(t) landed (only stage(t+1) may remain)
//   ds_read frags(t)
//   s_barrier               <- all waves' reads of buf[t&1] issued
//   stage(t+2) -> buf[t&1]  <- its LDS writes arrive >=300cyc later; safe
//   setprio(1); 32 MFMA; setprio(0)
// Prologue stages tiles 0,1 (8 loads); top-of-iter-0 vmcnt(4) waits tile 0.
// Tail: t=nt-1 waits vmcnt(0) (no stage(nt) ever issued). nt >= 2 required.
template<int MODE>
__global__ __launch_bounds__(512, 4) void gemm256tlp(
        const short* __restrict__ A, int lda, long strideA,
        const short* __restrict__ B, int ldb,
        void* __restrict__ OutA, void* __restrict__ OutB,
        int ldo, long strideO,
        int K,
        const float* __restrict__ biasK, const float* __restrict__ biasV,
        const float* __restrict__ mask, long strideMask) {
    __shared__ short lds[2 * 16384];          // 2 bufs x 32 KiB = 64 KiB
    int tid = threadIdx.x;
    int wave = tid >> 6, lane = tid & 63;
    int bx, by, bz;
    xcd_remap(bx, by, bz);
    int n0 = bx * 256;
    int m0 = by * 256;
    int z = bz;

    const short* Ab = A + (long)z * strideA;
    const short* Bb;
    if (MODE == 4) Bb = B + (long)z * 1048576;
    else           Bb = B;                    // concatenated weights, shared

    f32x4 acc[8][4];
    #pragma unroll
    for (int i = 0; i < 8; ++i)
        #pragma unroll
        for (int j = 0; j < 4; ++j) {
            f32x4 zz = {0.f, 0.f, 0.f, 0.f};
            acc[i][j] = zz;
        }

    int wm = wave >> 2, wn = wave & 3;        // 2 x 4 wave grid
    int r = lane & 15, q = lane >> 4;

    // Per-thread staging: 4 chunks (it 0,1 -> A; 2,3 -> B), 2048 chunks/tile.
    const short* sp0; const short* sp1; const short* sp2; const short* sp3;
    int lo0, lo1, lo2, lo3;
    {
        #pragma unroll
        for (int it = 0; it < 4; ++it) {
            int cid = it * 512 + tid;          // 0..2047
            int rid = cid & 1023;
            int srow = rid >> 3;               // 0..127
            int scol = rid & 7;
            int scol0 = scol ^ (srow & 7);
            int row = srow * 2 + (scol0 >> 2);
            int col = (scol0 & 3) << 3;
            const short* p = (cid < 1024)
                ? (Ab + (long)(m0 + row) * lda + col)
                : (Bb + (long)(n0 + row) * ldb + col);
            int lo = cid * 8;
            if (it == 0) { sp0 = p; lo0 = lo; }
            else if (it == 1) { sp1 = p; lo1 = lo; }
            else if (it == 2) { sp2 = p; lo2 = lo; }
            else { sp3 = p; lo3 = lo; }
        }
    }

    // Fragment LDS offsets (shorts). A region [0,8192), B region [8192,16384).
    int offA[8], offB[4];
    #pragma unroll
    for (int i = 0; i < 8; ++i) {
        int rowA = wm * 128 + i * 16 + r;
        int srow = rowA >> 1;
        int slot = ((((rowA & 1) << 2) | q) ^ (srow & 7));
        offA[i] = srow * 64 + slot * 8;
    }
    #pragma unroll
    for (int j = 0; j < 4; ++j) {
        int rowB = wn * 64 + j * 16 + r;
        int srow = rowB >> 1;
        int slot = ((((rowB & 1) << 2) | q) ^ (srow & 7));
        offB[j] = 8192 + srow * 64 + slot * 8;
    }

    int nt = K >> 5;                           // nt >= 16 at our call sites
    // Prologue: stage tiles 0 and 1.
    async_cp16(sp0 +  0, &lds[lo0]);
    async_cp16(sp1 +  0, &lds[lo1]);
    async_cp16(sp2 +  0, &lds[lo2]);
    async_cp16(sp3 +  0, &lds[lo3]);
    async_cp16(sp0 + 32, &lds[16384 + lo0]);
    async_cp16(sp1 + 32, &lds[16384 + lo1]);
    async_cp16(sp2 + 32, &lds[16384 + lo2]);
    async_cp16(sp3 + 32, &lds[16384 + lo3]);

    for (int t = 0; t < nt; ++t) {
        if (t + 1 < nt)
            asm volatile("s_waitcnt vmcnt(4)\n\ts_barrier" ::: "memory");
        else
            asm volatile("s_waitcnt vmcnt(0)\n\ts_barrier" ::: "memory");
        const short* base = &lds[(t & 1) * 16384];
        s16x8 af[8], bfr[4];
        #pragma unroll
        for (int j = 0; j < 4; ++j) bfr[j] = *(const s16x8*)&base[offB[j]];
        #pragma unroll
        for (int i = 0; i < 8; ++i) af[i] = *(const s16x8*)&base[offA[i]];
        asm volatile("s_barrier" ::: "memory");   // reads issued before re-stage
        if (t + 2 < nt) {
            int ks = (t + 2) << 5;
            short* d = &lds[(t & 1) * 16384];
            async_cp16(sp0 + ks, d + lo0);
            async_cp16(sp1 + ks, d + lo1);
            async_cp16(sp2 + ks, d + lo2);
            async_cp16(sp3 + ks, d + lo3);
        }
        __builtin_amdgcn_s_setprio(1);
        #pragma unroll
        for (int i = 0; i < 8; ++i)
            #pragma unroll
            for (int j = 0; j < 4; ++j)
                acc[i][j] = __builtin_amdgcn_mfma_f32_16x16x32_bf16(af[i], bfr[j], acc[i][j], 0, 0, 0);
        __builtin_amdgcn_s_setprio(0);
    }

    // Epilogue: C/D layout col = lane&15, row = (lane>>4)*4 + reg
    #pragma unroll
    for (int i = 0; i < 8; ++i) {
        int gmb = m0 + wm * 128 + i * 16 + q * 4;
        #pragma unroll
        for (int j = 0; j < 4; ++j) {
            int gn = n0 + wn * 64 + j * 16 + r;
            #pragma unroll
            for (int rg = 0; rg < 4; ++rg) {
                int row = gmb + rg;
                float v = acc[i][j][rg];
                if (MODE == 0) {
                    if (gn < 1024) {
                        ((short*)OutA)[(long)z * strideO + (long)row * ldo + gn] =
                            f2b(v + biasK[gn]);
                    } else {
                        int gv = gn - 1024;
                        float mk = mask[(long)z * strideMask + row];
                        ((short*)OutB)[(long)z * strideO + (long)row * ldo + gv] =
                            f2b((v + biasV[gv]) * mk);
                    }
                } else {
                    ((float*)OutA)[(long)z * strideO + (long)row * ldo + gn] =
                        v + biasK[gn];
                }
            }
        }
    }
}

// ---------------------------------------------------------------------------
// Split-K fused column-softmax + linear-attention KV partial:
// pbuf[z,ns][l][d] = sum_{n in slice ns} exp(klog+pen-M)[n,d] * v[n,l]  (f32)
__global__ __launch_bounds__(256) void attn_part(const short* __restrict__ klog,
                                                 const short* __restrict__ vbuf,
                                                 const float* __restrict__ cmask,
                                                 const float* __restrict__ smask,
                                                 const float* __restrict__ Ms,
                                                 float* __restrict__ pbuf) {
    __shared__ short kT[128 * 64];
    __shared__ short vT[128 * 64];
    int ns = blockIdx.x;
    int z = blockIdx.y;
    int b = z >> 3, h = z & 7;
    int tid = threadIdx.x;
    int wave = tid >> 6, lane = tid & 63;
    int r = lane & 15, q = lane >> 4;
    int wm = wave >> 1, wn = wave & 1;

    int cg = h * 128 + lane * 2;
    float M0 = Ms[b * 1024 + cg];
    float M1 = Ms[b * 1024 + cg + 1];

    f32x4 acc[4][4];
    #pragma unroll
    for (int i = 0; i < 4; ++i)
        #pragma unroll
        for (int j = 0; j < 4; ++j) {
            f32x4 zz = {0.f, 0.f, 0.f, 0.f};
            acc[i][j] = zz;
        }

    long base = ((long)b * 2560) * 1024 + h * 128;
    int nbase = ns * 320;
    int swz = (lane & 7) << 3;
    for (int n0 = 0; n0 < 320; n0 += 64) {
        __syncthreads();
        #pragma unroll 4
        for (int i = 0; i < 16; ++i) {
            int nl = i * 4 + wave;
            int n = nbase + n0 + nl;
            float pen = pen_of(cmask, smask, b, n);
            long g = base + (long)n * 1024 + lane * 2;
            short2 k2 = *(const short2*)&klog[g];
            short2 v2 = *(const short2*)&vbuf[g];
            float w0 = __expf(b2f(k2.x) + pen - M0);
            float w1 = __expf(b2f(k2.y) + pen - M1);
            int c = lane * 2;
            int sw = nl ^ swz;
            kT[c * 64 + sw] = f2b(w0);
            kT[(c + 1) * 64 + sw] = f2b(w1);
            vT[c * 64 + sw] = v2.x;
            vT[(c + 1) * 64 + sw] = v2.y;
        }
        __syncthreads();
        #pragma unroll
        for (int kk = 0; kk < 64; kk += 32) {
            s16x8 af[4], bfr[4];
            #pragma unroll
            for (int i = 0; i < 4; ++i) {
                int cA = wm * 64 + i * 16 + r;
                int cB = wn * 64 + i * 16 + r;
                af[i]  = *(const s16x8*)&kT[cA * 64 + ((kk + q * 8) ^ (((cA >> 1) & 7) << 3))];
                bfr[i] = *(const s16x8*)&vT[cB * 64 + ((kk + q * 8) ^ (((cB >> 1) & 7) << 3))];
            }
            #pragma unroll
            for (int i = 0; i < 4; ++i)
                #pragma unroll
                for (int j = 0; j < 4; ++j)
                    acc[i][j] = __builtin_amdgcn_mfma_f32_16x16x32_bf16(af[i], bfr[j], acc[i][j], 0, 0, 0);
        }
    }
    float* outp = pbuf + ((long)z * 8 + ns) * 16384;
    #pragma unroll
    for (int i = 0; i < 4; ++i) {
        int d0 = wm * 64 + i * 16 + q * 4;
        #pragma unroll
        for (int j = 0; j < 4; ++j) {
            int l = wn * 64 + j * 16 + r;
            *(f32x4*)&outp[l * 128 + d0] = acc[i][j];
        }
    }
}

// Sum the 8 partials, apply 1/S (per d), emit bf16 attnD[z][d][l] (d-major!).
__global__ __launch_bounds__(256) void reduce_attn(const float* __restrict__ pbuf,
                                                   const float* __restrict__ iSs,
                                                   short* __restrict__ attnD) {
    int idx = blockIdx.x * 256 + threadIdx.x;   // over 64*16384
    int z = idx >> 14, rem = idx & 16383;
    int d = rem & 127, l = rem >> 7;
    int b = z >> 3, h = z & 7;
    const float* p = pbuf + (long)z * 8 * 16384 + rem;
    float s = 0.f;
    #pragma unroll
    for (int ns = 0; ns < 8; ++ns) s += p[ns * 16384];
    attnD[(long)z * 16384 + d * 128 + l] = f2b(s * iSs[b * 1024 + h * 128 + d]);
}

// ---------------------------------------------------------------------------
extern "C" void kernel_launch(void* const* d_in, const int* in_sizes, int n_in,
                              void* d_out, int out_size, void* d_ws, size_t ws_size,
                              hipStream_t stream) {
    const float* query = (const float*)d_in[0];
    const float* x     = (const float*)d_in[1];
    const float* cond  = (const float*)d_in[2];
    const float* smask = (const float*)d_in[3];
    const float* cmask = (const float*)d_in[4];
    const float* gx  = (const float*)d_in[5];
    const float* bx  = (const float*)d_in[6];
    const float* gc  = (const float*)d_in[7];
    const float* bc  = (const float*)d_in[8];
    const float* Wkc = (const float*)d_in[9];
    const float* bkc = (const float*)d_in[10];
    const float* Wvc = (const float*)d_in[11];
    const float* bvc = (const float*)d_in[12];
    const float* Wkx = (const float*)d_in[13];
    const float* bkx = (const float*)d_in[14];
    const float* Wvx = (const float*)d_in[15];
    const float* bvx = (const float*)d_in[16];
    const float* Wy  = (const float*)d_in[17];
    const float* by  = (const float*)d_in[18];

    // Workspace layout (bytes) — identical 'need' to the passing r3/r4 runs.
    size_t o_xn    = 0;                      // 33,554,432 (pbuf alias)
    size_t o_cn    = o_xn    + 33554432;     //  4,194,304
    size_t o_klog  = o_cn    + 4194304;      // 41,943,040 (Zt alias after attn)
    size_t o_vbuf  = o_klog  + 41943040;     // 41,943,040
    size_t o_qsm   = o_vbuf  + 41943040;     // 33,554,432
    size_t o_attnD = o_qsm   + 33554432;     //  2,097,152
    size_t o_partM = o_attnD + 2097152;      //    327,680
    size_t o_partS = o_partM + 327680;       //    327,680
    size_t o_Ms    = o_partS + 327680;       //     32,768
    size_t o_iSs   = o_Ms    + 32768;        //     32,768
    size_t o_wkc   = o_iSs   + 32768;        //  1,048,576  } weights contiguous
    size_t o_wvc   = o_wkc   + 1048576;      //  1,048,576  }
    size_t o_wkx   = o_wvc   + 1048576;      //  2,097,152  }
    size_t o_wvx   = o_wkx   + 2097152;      //  2,097,152  }
    size_t o_wy    = o_wvx   + 2097152;      //  2,097,152  }
    size_t need    = o_wy    + 2097152;      // = 166,395,904
    if (ws_size < need) return;  // clean no-op -> diagnosable absmax failure

    char* w = (char*)d_ws;
    short* xn    = (short*)(w + o_xn);
    short* cn    = (short*)(w + o_cn);
    short* klog  = (short*)(w + o_klog);
    short* vbuf  = (short*)(w + o_vbuf);
    short* qsm   = (short*)(w + o_qsm);
    short* attnD = (short*)(w + o_attnD);
    float* partM = (float*)(w + o_partM);
    float* partS = (float*)(w + o_partS);
    float* Ms    = (float*)(w + o_Ms);
    float* iSs   = (float*)(w + o_iSs);
    short* wkc   = (short*)(w + o_wkc);   // [wkc|wvc] = cat B for cond KV GEMM
    short* wkx   = (short*)(w + o_wkx);   // [wkx|wvx] = cat B for x KV GEMM
    short* wy    = (short*)(w + o_wy);
    float* pbuf  = (float*)xn;            // xn dead after KV GEMMs
    short* Zt    = klog;                  // klog dead after attn_part

    // Allow 128 KiB dynamic LDS for the OUT 256^2 ring (host-side, capture-safe).
    static bool attr_set = false;
    if (!attr_set) {
        (void)hipFuncSetAttribute((const void*)gemm256<4>,
                                  hipFuncAttributeMaxDynamicSharedMemorySize, 131072);
        attr_set = true;
    }

    // Weight conversion f32 -> bf16 (single launch; dst region is contiguous)
    cvt_all<<<4096, 256, 0, stream>>>(Wkc, Wvc, Wkx, Wvx, Wy, wkc);

    ln_kernel<<<16384, 256, 0, stream>>>(x, gx, bx, xn, 1024);
    ln_kernel<<<4096, 256, 0, stream>>>(cond, gc, bc, cn, 512);
    qsoftmax_kernel<<<32768, 256, 0, stream>>>(query, qsm);

    // Fused k+v projection, x source: N=2048 (k|v), K=1024, M=2048/b, z=8
    // 256^2-tile 2-buffer TLP kernel: 512 blocks -> 2 blocks/CU.
    gemm256tlp<0><<<dim3(8, 8, 8), 512, 0, stream>>>(
        xn, 1024, 2097152L, wkx, 1024,
        klog + 512 * 1024, vbuf + 512 * 1024, 1024, 2621440L,
        1024, bkx, bvx, smask, 2048L);
    // Fused k+v projection, cond source: N=2048, K=512, M=512/b, z=8 (128^2)
    gemm_bt<0><<<dim3(16, 4, 8), 256, 0, stream>>>(
        cn, 512, 262144L, wkc, 512,
        klog, vbuf, 1024, 2621440L,
        512, bkc, bvc, cmask, 512L);

    kstats1<<<dim3(4, 8, 10), 256, 0, stream>>>(klog, cmask, smask, partM, partS);
    kstats2<<<dim3(4, 8), 256, 0, stream>>>(partM, partS, Ms, iSs);

    // Split-K attention KV (pbuf overwrites xn region — xn dead by now)
    attn_part<<<dim3(8, 64), 256, 0, stream>>>(klog, vbuf, cmask, smask, Ms, pbuf);
    reduce_attn<<<4096, 256, 0, stream>>>(pbuf, iSs, attnD);

    // Zt[b][o][h*128+d] = sum_l Wy[o][h*128+l] * attnD[b,h][d][l]
    gemm_bt<2><<<dim3(1, 8, 64), 256, 0, stream>>>(
        wy, 1024, 0L, attnD, 128,
        Zt, nullptr, 1024, 0L,
        128, nullptr, nullptr, nullptr, 0L);
    // out[b] = qsm[b] @ Zt[b]^T + by   (f32 out, 256^2 4-buf ring, 1 blk/CU)
    gemm256<4><<<dim3(4, 8, 8), 512, 131072, stream>>>(
        qsm, 1024, 2097152L, Zt, 1024,
        d_out, nullptr, 1024, 2097152L,
        1024, by, nullptr, nullptr, 0L);
}

// Round 6
// 473.202 us; speedup vs baseline: 2.2897x; 2.2897x over previous
//
#include <hip/hip_runtime.h>

// ---------------------------------------------------------------------------
// SubAttention fused pipeline for MI355X (gfx950). f32 I/O, bf16 MFMA compute.
// B=8 T=2048 Tc=512 D=1024 Dc=512 H=8 hd=128 N=2560
// R5 lesson: __launch_bounds__(512,4) on the 256^2 kernel spills the 128-VGPR
// accumulator (VGPR capped 128 < ~190 needed) -> 3.3 GB scratch traffic.
// 256^2 @ 2 blocks/CU is register-infeasible; ring kernels below are verified.
// ---------------------------------------------------------------------------

typedef short s16x8 __attribute__((ext_vector_type(8)));
typedef float f32x4 __attribute__((ext_vector_type(4)));

__device__ __forceinline__ float b2f(short s) {
    unsigned int u = ((unsigned int)(unsigned short)s) << 16;
    return __uint_as_float(u);
}
__device__ __forceinline__ short f2b(float f) {
    unsigned int u = __float_as_uint(f);
    u += 0x7fffu + ((u >> 16) & 1u);   // round-to-nearest-even
    return (short)(u >> 16);
}

typedef void __attribute__((address_space(1)))* gas_ptr;
typedef void __attribute__((address_space(3)))* las_ptr;
__device__ __forceinline__ void async_cp16(const void* g, void* l) {
    __builtin_amdgcn_global_load_lds((gas_ptr)g, (las_ptr)l, 16, 0, 0);
}

__device__ __forceinline__ float pen_of(const float* __restrict__ cmask,
                                        const float* __restrict__ smask,
                                        int b, int n) {
    float mk = (n < 512) ? cmask[b * 512 + n] : smask[b * 2048 + n - 512];
    return (1.0f - mk) * -1000000.0f;
}

// XCD-aware bijective block remap: keeps panel-sharing groups on one XCD's L2.
// Requires (gridDim.y*gridDim.z) % 8 == 0 (all our grids comply).
__device__ __forceinline__ void xcd_remap(int& gx, int& gy, int& gz) {
    int lb = blockIdx.x + gridDim.x * (blockIdx.y + gridDim.y * blockIdx.z);
    int nx = gridDim.x;
    int gpx = (gridDim.y * gridDim.z) >> 3;
    int xcd = lb & 7, rest = lb >> 3;
    gx = rest % nx;
    int gidx = xcd * gpx + rest / nx;
    gy = gidx % gridDim.y;
    gz = gidx / gridDim.y;
}

// ---------------------------------------------------------------------------
// One-shot f32->bf16 weight conversion into the contiguous ws weight region:
// [wkc 512K][wvc 512K][wkx 1M][wvx 1M][wy 1M] elements.
__global__ __launch_bounds__(256) void cvt_all(const float* __restrict__ Wkc,
                                               const float* __restrict__ Wvc,
                                               const float* __restrict__ Wkx,
                                               const float* __restrict__ Wvx,
                                               const float* __restrict__ Wy,
                                               short* __restrict__ dst) {
    int g = (blockIdx.x * 256 + threadIdx.x) * 4;     // 0 .. 4194300
    const float* src;
    if (g < 524288)        src = Wkc + g;
    else if (g < 1048576)  src = Wvc + (g - 524288);
    else if (g < 2097152)  src = Wkx + (g - 1048576);
    else if (g < 3145728)  src = Wvx + (g - 2097152);
    else                   src = Wy  + (g - 3145728);
    float4 v = *(const float4*)src;
    short4 o;
    o.x = f2b(v.x); o.y = f2b(v.y); o.z = f2b(v.z); o.w = f2b(v.w);
    *(short4*)&dst[g] = o;
}

// ---------------------------------------------------------------------------
// LayerNorm: one row (length L = 1024 or 512) per block of 256 threads.
__global__ __launch_bounds__(256) void ln_kernel(const float* __restrict__ x,
                                                 const float* __restrict__ g,
                                                 const float* __restrict__ be,
                                                 short* __restrict__ out, int L) {
    long row = blockIdx.x;
    const float* xr = x + row * L;
    short* orow = out + row * L;
    int tid = threadIdx.x;
    int i0 = tid * 4;
    bool active = i0 < L;
    float v0 = 0.f, v1 = 0.f, v2 = 0.f, v3 = 0.f;
    if (active) {
        float4 p = *(const float4*)&xr[i0];
        v0 = p.x; v1 = p.y; v2 = p.z; v3 = p.w;
    }
    float s = v0 + v1 + v2 + v3;
    float s2 = v0*v0 + v1*v1 + v2*v2 + v3*v3;
    #pragma unroll
    for (int off = 32; off > 0; off >>= 1) {
        s  += __shfl_down(s, off);
        s2 += __shfl_down(s2, off);
    }
    __shared__ float ss[4], sq[4];
    int wave = tid >> 6, lane = tid & 63;
    if (lane == 0) { ss[wave] = s; sq[wave] = s2; }
    __syncthreads();
    if (tid == 0) {
        float t1 = ss[0] + ss[1] + ss[2] + ss[3];
        float t2 = sq[0] + sq[1] + sq[2] + sq[3];
        float mu = t1 / (float)L;
        float var = t2 / (float)L - mu * mu;
        ss[0] = mu;
        sq[0] = rsqrtf(var + 1e-5f);
    }
    __syncthreads();
    float mu = ss[0], rs = sq[0];
    if (active) {
        float4 gp = *(const float4*)&g[i0];
        float4 bp = *(const float4*)&be[i0];
        short4 o;
        o.x = f2b((v0 - mu) * rs * gp.x + bp.x);
        o.y = f2b((v1 - mu) * rs * gp.y + bp.y);
        o.z = f2b((v2 - mu) * rs * gp.z + bp.z);
        o.w = f2b((v3 - mu) * rs * gp.w + bp.w);
        *(short4*)&orow[i0] = o;
    }
}

// ---------------------------------------------------------------------------
// q softmax over last axis (rows of 128 f32). 4 rows per block (1 wave each).
__global__ __launch_bounds__(256) void qsoftmax_kernel(const float* __restrict__ q,
                                                       short* __restrict__ out) {
    long row = (long)blockIdx.x * 4 + (threadIdx.x >> 6);
    int lane = threadIdx.x & 63;
    const float* qr = q + row * 128;
    float2 p = *(const float2*)&qr[lane * 2];
    float v0 = p.x, v1 = p.y;
    float m = fmaxf(v0, v1);
    #pragma unroll
    for (int off = 32; off > 0; off >>= 1) m = fmaxf(m, __shfl_xor(m, off));
    float e0 = __expf(v0 - m), e1 = __expf(v1 - m);
    float s = e0 + e1;
    #pragma unroll
    for (int off = 32; off > 0; off >>= 1) s += __shfl_xor(s, off);
    float inv = 1.0f / s;
    short2 o; o.x = f2b(e0 * inv); o.y = f2b(e1 * inv);
    *(short2*)&out[row * 128 + lane * 2] = o;
}

// ---------------------------------------------------------------------------
// Column-softmax stats over n (N=2560). 40 slices of 64 n each -> 1280 blocks
// (5/CU TLP), 4 interleaved online accumulators (serial exp chain 256 -> 16).
__global__ __launch_bounds__(256) void kstats1(const short* __restrict__ klog,
                                               const float* __restrict__ cmask,
                                               const float* __restrict__ smask,
                                               float* __restrict__ partM,
                                               float* __restrict__ partS) {
    int c = blockIdx.x * 256 + threadIdx.x;
    int b = blockIdx.y;
    int n0 = blockIdx.z * 64;
    const short* base = klog + (long)b * 2560 * 1024 + c;
    float m0 = -3.4e38f, m1 = -3.4e38f, m2 = -3.4e38f, m3 = -3.4e38f;
    float s0 = 0.f, s1 = 0.f, s2 = 0.f, s3 = 0.f;
    #pragma unroll 4
    for (int k = 0; k < 16; ++k) {
        int n = n0 + k * 4;
        float v0 = b2f(base[(long)(n + 0) * 1024]) + pen_of(cmask, smask, b, n + 0);
        float v1 = b2f(base[(long)(n + 1) * 1024]) + pen_of(cmask, smask, b, n + 1);
        float v2 = b2f(base[(long)(n + 2) * 1024]) + pen_of(cmask, smask, b, n + 2);
        float v3 = b2f(base[(long)(n + 3) * 1024]) + pen_of(cmask, smask, b, n + 3);
        float nm;
        nm = fmaxf(m0, v0); s0 = s0 * __expf(m0 - nm) + __expf(v0 - nm); m0 = nm;
        nm = fmaxf(m1, v1); s1 = s1 * __expf(m1 - nm) + __expf(v1 - nm); m1 = nm;
        nm = fmaxf(m2, v2); s2 = s2 * __expf(m2 - nm) + __expf(v2 - nm); m2 = nm;
        nm = fmaxf(m3, v3); s3 = s3 * __expf(m3 - nm) + __expf(v3 - nm); m3 = nm;
    }
    float M = fmaxf(fmaxf(m0, m1), fmaxf(m2, m3));
    float S = s0 * __expf(m0 - M) + s1 * __expf(m1 - M) +
              s2 * __expf(m2 - M) + s3 * __expf(m3 - M);
    long o = ((long)(b * 40 + blockIdx.z)) * 1024 + c;
    partM[o] = M;
    partS[o] = S;
}

__global__ __launch_bounds__(256) void kstats2(const float* __restrict__ partM,
                                               const float* __restrict__ partS,
                                               float* __restrict__ Ms,
                                               float* __restrict__ iSs) {
    int c = blockIdx.x * 256 + threadIdx.x;
    int b = blockIdx.y;
    float M = -3.4e38f;
    #pragma unroll 8
    for (int k = 0; k < 40; ++k)
        M = fmaxf(M, partM[((long)(b * 40 + k)) * 1024 + c]);
    float S = 0.f;
    #pragma unroll 8
    for (int k = 0; k < 40; ++k) {
        long o = ((long)(b * 40 + k)) * 1024 + c;
        S += partS[o] * __expf(partM[o] - M);
    }
    Ms[b * 1024 + c] = M;
    iSs[b * 1024 + c] = 1.0f / S;
}

// ---------------------------------------------------------------------------
// 128x128-tile bf16 MFMA B^T GEMM. BK=32, 4-buffer LDS ring (64 KiB),
// counted-vmcnt depth-3 prefetch, ONE barrier per K-tile. Verified R2-R4.
// MODE 0 (KV) : dual output. n<1024: OutA = bf16(acc + biasK[n]);
//               n>=1024: OutB = bf16((acc + biasV[n-1024]) * mask[row]).
// MODE 2 (ZT) : z=(b,h); OutA[b][row][h*128+n] = bf16(acc)
// MODE 4 (OUT): f32 OutA = acc + biasK[n], batched over z
template<int MODE>
__global__ __launch_bounds__(256) void gemm_bt(
        const short* __restrict__ A, int lda, long strideA,
        const short* __restrict__ B, int ldb,
        void* __restrict__ OutA, void* __restrict__ OutB,
        int ldo, long strideO,
        int K,
        const float* __restrict__ biasK, const float* __restrict__ biasV,
        const float* __restrict__ mask, long strideMask) {
    __shared__ short lds[4 * 8192];           // 4 bufs x 16 KiB
    int tid = threadIdx.x;
    int wave = tid >> 6, lane = tid & 63;
    int bx, by, bz;
    xcd_remap(bx, by, bz);
    int n0 = bx * 128;
    int m0 = by * 128;
    int z = bz;

    const short* Ab;
    const short* Bb;
    if (MODE == 2) {
        Ab = A + (z & 7) * 128;             // Wy columns h*128..h*128+127
        Bb = B + (long)z * 16384;           // attnD[z] (128 x 128)
    } else if (MODE == 4) {
        Ab = A + (long)z * strideA;         // qsm[b]
        Bb = B + (long)z * 1048576;         // Zt[b]
    } else {
        Ab = A + (long)z * strideA;
        Bb = B;                             // concatenated weights, shared
    }

    f32x4 acc[4][4];
    #pragma unroll
    for (int i = 0; i < 4; ++i)
        #pragma unroll
        for (int j = 0; j < 4; ++j) {
            f32x4 zz = {0.f, 0.f, 0.f, 0.f};
            acc[i][j] = zz;
        }

    int wm = wave >> 1, wn = wave & 1;
    int r = lane & 15, q = lane >> 4;

    // Per-thread staging: 4 chunks (it 0,1 -> A; 2,3 -> B), 1024 chunks total.
    const short* sp0; const short* sp1; const short* sp2; const short* sp3;
    int lo0, lo1, lo2, lo3;
    {
        #pragma unroll
        for (int it = 0; it < 4; ++it) {
            int cid = it * 256 + tid;          // 0..1023
            int rid = cid & 511;
            int srow = rid >> 3;               // 0..63
            int scol = rid & 7;
            int scol0 = scol ^ (srow & 7);
            int row = srow * 2 + (scol0 >> 2);
            int col = (scol0 & 3) << 3;
            const short* p = (cid < 512)
                ? (Ab + (long)(m0 + row) * lda + col)
                : (Bb + (long)(n0 + row) * ldb + col);
            int lo = cid * 8;
            if (it == 0) { sp0 = p; lo0 = lo; }
            else if (it == 1) { sp1 = p; lo1 = lo; }
            else if (it == 2) { sp2 = p; lo2 = lo; }
            else { sp3 = p; lo3 = lo; }
        }
    }

    // Fragment LDS offsets (shorts). A region [0,4096), B region [4096,8192).
    int offA[4], offB[4];
    #pragma unroll
    for (int i = 0; i < 4; ++i) {
        int rowA = wm * 64 + i * 16 + r;
        int srow = rowA >> 1;
        int slot = ((((rowA & 1) << 2) | q) ^ (srow & 7));
        offA[i] = srow * 64 + slot * 8;
        int rowB = wn * 64 + i * 16 + r;
        int srowB = rowB >> 1;
        int slotB = ((((rowB & 1) << 2) | q) ^ (srowB & 7));
        offB[i] = 4096 + srowB * 64 + slotB * 8;
    }

    int nt = K >> 5;                           // K-tiles of 32 (K>=128 -> nt>=4)
    // Prologue: stage tiles 0,1,2 into bufs 0,1,2.
    #pragma unroll
    for (int pt = 0; pt < 3; ++pt) {
        async_cp16(sp0 + (pt << 5), &lds[pt * 8192 + lo0]);
        async_cp16(sp1 + (pt << 5), &lds[pt * 8192 + lo1]);
        async_cp16(sp2 + (pt << 5), &lds[pt * 8192 + lo2]);
        async_cp16(sp3 + (pt << 5), &lds[pt * 8192 + lo3]);
    }

    for (int t = 0; t < nt; ++t) {
        if (t + 2 < nt)
            asm volatile("s_waitcnt vmcnt(8)\n\ts_barrier" ::: "memory");
        else if (t + 1 < nt)
            asm volatile("s_waitcnt vmcnt(4)\n\ts_barrier" ::: "memory");
        else
            asm volatile("s_waitcnt vmcnt(0)\n\ts_barrier" ::: "memory");
        const short* base = &lds[(t & 3) * 8192];
        s16x8 af[4], bfr[4];
        #pragma unroll
        for (int j = 0; j < 4; ++j) bfr[j] = *(const s16x8*)&base[offB[j]];
        #pragma unroll
        for (int i = 0; i < 4; ++i) af[i] = *(const s16x8*)&base[offA[i]];
        if (t + 3 < nt) {
            int buf = (t + 3) & 3;
            int ks = (t + 3) << 5;
            async_cp16(sp0 + ks, &lds[buf * 8192 + lo0]);
            async_cp16(sp1 + ks, &lds[buf * 8192 + lo1]);
            async_cp16(sp2 + ks, &lds[buf * 8192 + lo2]);
            async_cp16(sp3 + ks, &lds[buf * 8192 + lo3]);
        }
        __builtin_amdgcn_s_setprio(1);
        #pragma unroll
        for (int i = 0; i < 4; ++i)
            #pragma unroll
            for (int j = 0; j < 4; ++j)
                acc[i][j] = __builtin_amdgcn_mfma_f32_16x16x32_bf16(af[i], bfr[j], acc[i][j], 0, 0, 0);
        __builtin_amdgcn_s_setprio(0);
    }

    // Epilogue: C/D layout col = lane&15, row = (lane>>4)*4 + reg  [m89/m91]
    #pragma unroll
    for (int i = 0; i < 4; ++i) {
        int gmb = m0 + wm * 64 + i * 16 + q * 4;
        #pragma unroll
        for (int j = 0; j < 4; ++j) {
            int gn = n0 + wn * 64 + j * 16 + r;
            #pragma unroll
            for (int rg = 0; rg < 4; ++rg) {
                int row = gmb + rg;
                float v = acc[i][j][rg];
                if (MODE == 0) {
                    if (gn < 1024) {
                        ((short*)OutA)[(long)z * strideO + (long)row * ldo + gn] =
                            f2b(v + biasK[gn]);
                    } else {
                        int gv = gn - 1024;
                        float mk = mask[(long)z * strideMask + row];
                        ((short*)OutB)[(long)z * strideO + (long)row * ldo + gv] =
                            f2b((v + biasV[gv]) * mk);
                    }
                } else if (MODE == 2) {
                    ((short*)OutA)[(long)(z >> 3) * 1048576 + (long)row * 1024 +
                                   (z & 7) * 128 + gn] = f2b(v);
                } else {
                    ((float*)OutA)[(long)z * strideO + (long)row * ldo + gn] =
                        v + biasK[gn];
                }
            }
        }
    }
}

// ---------------------------------------------------------------------------
// 256x256-tile, 8-wave, BK=32 4-buffer ring (128 KiB dynamic, 1 block/CU).
// Verified best-per-block pipeline (R2: 592 TF effective on KVx).
// MODE 0 (KV) : dual output, same semantics as gemm_bt<0>.
// MODE 4 (OUT): f32 OutA = acc + biasK[n], B batched per z (stride 1M elems).
template<int MODE>
__global__ __launch_bounds__(512, 2) void gemm256(
        const short* __restrict__ A, int lda, long strideA,
        const short* __restrict__ B, int ldb,
        void* __restrict__ OutA, void* __restrict__ OutB,
        int ldo, long strideO,
        int K,
        const float* __restrict__ biasK, const float* __restrict__ biasV,
        const float* __restrict__ mask, long strideMask) {
    extern __shared__ short lds[];            // 4 bufs x 16384 shorts
    int tid = threadIdx.x;
    int wave = tid >> 6, lane = tid & 63;
    int bx, by, bz;
    xcd_remap(bx, by, bz);
    int n0 = bx * 256;
    int m0 = by * 256;
    int z = bz;

    const short* Ab;
    const short* Bb;
    if (MODE == 4) {
        Ab = A + (long)z * strideA;           // qsm[b]
        Bb = B + (long)z * 1048576;           // Zt[b]
    } else {
        Ab = A + (long)z * strideA;
        Bb = B;                               // concatenated weights, shared
    }

    f32x4 acc[8][4];
    #pragma unroll
    for (int i = 0; i < 8; ++i)
        #pragma unroll
        for (int j = 0; j < 4; ++j) {
            f32x4 zz = {0.f, 0.f, 0.f, 0.f};
            acc[i][j] = zz;
        }

    int wm = wave >> 2, wn = wave & 3;        // 2 x 4 wave grid
    int r = lane & 15, q = lane >> 4;

    const short* sp0; const short* sp1; const short* sp2; const short* sp3;
    int lo0, lo1, lo2, lo3;
    {
        #pragma unroll
        for (int it = 0; it < 4; ++it) {
            int cid = it * 512 + tid;          // 0..2047
            int rid = cid & 1023;
            int srow = rid >> 3;               // 0..127
            int scol = rid & 7;
            int scol0 = scol ^ (srow & 7);
            int row = srow * 2 + (scol0 >> 2);
            int col = (scol0 & 3) << 3;
            const short* p = (cid < 1024)
                ? (Ab + (long)(m0 + row) * lda + col)
                : (Bb + (long)(n0 + row) * ldb + col);
            int lo = cid * 8;
            if (it == 0) { sp0 = p; lo0 = lo; }
            else if (it == 1) { sp1 = p; lo1 = lo; }
            else if (it == 2) { sp2 = p; lo2 = lo; }
            else { sp3 = p; lo3 = lo; }
        }
    }

    int offA[8], offB[4];
    #pragma unroll
    for (int i = 0; i < 8; ++i) {
        int rowA = wm * 128 + i * 16 + r;
        int srow = rowA >> 1;
        int slot = ((((rowA & 1) << 2) | q) ^ (srow & 7));
        offA[i] = srow * 64 + slot * 8;
    }
    #pragma unroll
    for (int j = 0; j < 4; ++j) {
        int rowB = wn * 64 + j * 16 + r;
        int srow = rowB >> 1;
        int slot = ((((rowB & 1) << 2) | q) ^ (srow & 7));
        offB[j] = 8192 + srow * 64 + slot * 8;
    }

    int nt = K >> 5;                           // K>=512 here -> nt>=16
    #pragma unroll
    for (int pt = 0; pt < 3; ++pt) {
        async_cp16(sp0 + (pt << 5), &lds[pt * 16384 + lo0]);
        async_cp16(sp1 + (pt << 5), &lds[pt * 16384 + lo1]);
        async_cp16(sp2 + (pt << 5), &lds[pt * 16384 + lo2]);
        async_cp16(sp3 + (pt << 5), &lds[pt * 16384 + lo3]);
    }

    for (int t = 0; t < nt; ++t) {
        if (t + 2 < nt)
            asm volatile("s_waitcnt vmcnt(8)\n\ts_barrier" ::: "memory");
        else if (t + 1 < nt)
            asm volatile("s_waitcnt vmcnt(4)\n\ts_barrier" ::: "memory");
        else
            asm volatile("s_waitcnt vmcnt(0)\n\ts_barrier" ::: "memory");
        const short* base = &lds[(t & 3) * 16384];
        s16x8 af[8], bfr[4];
        #pragma unroll
        for (int j = 0; j < 4; ++j) bfr[j] = *(const s16x8*)&base[offB[j]];
        #pragma unroll
        for (int i = 0; i < 8; ++i) af[i] = *(const s16x8*)&base[offA[i]];
        if (t + 3 < nt) {
            int buf = (t + 3) & 3;
            int ks = (t + 3) << 5;
            async_cp16(sp0 + ks, &lds[buf * 16384 + lo0]);
            async_cp16(sp1 + ks, &lds[buf * 16384 + lo1]);
            async_cp16(sp2 + ks, &lds[buf * 16384 + lo2]);
            async_cp16(sp3 + ks, &lds[buf * 16384 + lo3]);
        }
        __builtin_amdgcn_s_setprio(1);
        #pragma unroll
        for (int i = 0; i < 8; ++i)
            #pragma unroll
            for (int j = 0; j < 4; ++j)
                acc[i][j] = __builtin_amdgcn_mfma_f32_16x16x32_bf16(af[i], bfr[j], acc[i][j], 0, 0, 0);
        __builtin_amdgcn_s_setprio(0);
    }

    #pragma unroll
    for (int i = 0; i < 8; ++i) {
        int gmb = m0 + wm * 128 + i * 16 + q * 4;
        #pragma unroll
        for (int j = 0; j < 4; ++j) {
            int gn = n0 + wn * 64 + j * 16 + r;
            #pragma unroll
            for (int rg = 0; rg < 4; ++rg) {
                int row = gmb + rg;
                float v = acc[i][j][rg];
                if (MODE == 0) {
                    if (gn < 1024) {
                        ((short*)OutA)[(long)z * strideO + (long)row * ldo + gn] =
                            f2b(v + biasK[gn]);
                    } else {
                        int gv = gn - 1024;
                        float mk = mask[(long)z * strideMask + row];
                        ((short*)OutB)[(long)z * strideO + (long)row * ldo + gv] =
                            f2b((v + biasV[gv]) * mk);
                    }
                } else {
                    ((float*)OutA)[(long)z * strideO + (long)row * ldo + gn] =
                        v + biasK[gn];
                }
            }
        }
    }
}

// ---------------------------------------------------------------------------
// Split-K fused column-softmax + linear-attention KV partial:
// pbuf[z,ns][l][d] = sum_{n in slice ns} exp(klog+pen-M)[n,d] * v[n,l]  (f32)
// Staging: short4 (8B) loads, 8 iters (was short2 x 16 iters).
__global__ __launch_bounds__(256) void attn_part(const short* __restrict__ klog,
                                                 const short* __restrict__ vbuf,
                                                 const float* __restrict__ cmask,
                                                 const float* __restrict__ smask,
                                                 const float* __restrict__ Ms,
                                                 float* __restrict__ pbuf) {
    __shared__ short kT[128 * 64];
    __shared__ short vT[128 * 64];
    int ns = blockIdx.x;
    int z = blockIdx.y;
    int b = z >> 3, h = z & 7;
    int tid = threadIdx.x;
    int wave = tid >> 6, lane = tid & 63;
    int r = lane & 15, q = lane >> 4;
    int wm = wave >> 1, wn = wave & 1;

    int l5 = lane & 31;
    int c = l5 * 4;                          // 4 channels per lane
    float4 Mv = *(const float4*)&Ms[b * 1024 + h * 128 + c];

    f32x4 acc[4][4];
    #pragma unroll
    for (int i = 0; i < 4; ++i)
        #pragma unroll
        for (int j = 0; j < 4; ++j) {
            f32x4 zz = {0.f, 0.f, 0.f, 0.f};
            acc[i][j] = zz;
        }

    long base = ((long)b * 2560) * 1024 + h * 128;
    int nbase = ns * 320;
    int sw0x = ((l5 * 2) & 7) << 3;          // swizzle for channels c, c+1
    int sw1x = ((l5 * 2 + 1) & 7) << 3;      // swizzle for channels c+2, c+3
    for (int n0 = 0; n0 < 320; n0 += 64) {
        __syncthreads();
        #pragma unroll
        for (int i = 0; i < 8; ++i) {
            int nl = i * 8 + wave * 2 + (lane >> 5);   // rows 0..63, unique
            int n = nbase + n0 + nl;
            float pen = pen_of(cmask, smask, b, n);
            long g = base + (long)n * 1024 + c;
            short4 k4 = *(const short4*)&klog[g];
            short4 v4 = *(const short4*)&vbuf[g];
            float w0 = __expf(b2f(k4.x) + pen - Mv.x);
            float w1 = __expf(b2f(k4.y) + pen - Mv.y);
            float w2 = __expf(b2f(k4.z) + pen - Mv.z);
            float w3 = __expf(b2f(k4.w) + pen - Mv.w);
            int sw0 = nl ^ sw0x;
            int sw1 = nl ^ sw1x;
            kT[(c + 0) * 64 + sw0] = f2b(w0);
            kT[(c + 1) * 64 + sw0] = f2b(w1);
            kT[(c + 2) * 64 + sw1] = f2b(w2);
            kT[(c + 3) * 64 + sw1] = f2b(w3);
            vT[(c + 0) * 64 + sw0] = v4.x;
            vT[(c + 1) * 64 + sw0] = v4.y;
            vT[(c + 2) * 64 + sw1] = v4.z;
            vT[(c + 3) * 64 + sw1] = v4.w;
        }
        __syncthreads();
        #pragma unroll
        for (int kk = 0; kk < 64; kk += 32) {
            s16x8 af[4], bfr[4];
            #pragma unroll
            for (int i = 0; i < 4; ++i) {
                int cA = wm * 64 + i * 16 + r;
                int cB = wn * 64 + i * 16 + r;
                af[i]  = *(const s16x8*)&kT[cA * 64 + ((kk + q * 8) ^ (((cA >> 1) & 7) << 3))];
                bfr[i] = *(const s16x8*)&vT[cB * 64 + ((kk + q * 8) ^ (((cB >> 1) & 7) << 3))];
            }
            #pragma unroll
            for (int i = 0; i < 4; ++i)
                #pragma unroll
                for (int j = 0; j < 4; ++j)
                    acc[i][j] = __builtin_amdgcn_mfma_f32_16x16x32_bf16(af[i], bfr[j], acc[i][j], 0, 0, 0);
        }
    }
    float* outp = pbuf + ((long)z * 8 + ns) * 16384;
    #pragma unroll
    for (int i = 0; i < 4; ++i) {
        int d0 = wm * 64 + i * 16 + q * 4;
        #pragma unroll
        for (int j = 0; j < 4; ++j) {
            int l = wn * 64 + j * 16 + r;
            *(f32x4*)&outp[l * 128 + d0] = acc[i][j];
        }
    }
}

// Sum the 8 partials, apply 1/S (per d), emit bf16 attnD[z][d][l] (d-major!).
__global__ __launch_bounds__(256) void reduce_attn(const float* __restrict__ pbuf,
                                                   const float* __restrict__ iSs,
                                                   short* __restrict__ attnD) {
    int idx = blockIdx.x * 256 + threadIdx.x;   // over 64*16384
    int z = idx >> 14, rem = idx & 16383;
    int d = rem & 127, l = rem >> 7;
    int b = z >> 3, h = z & 7;
    const float* p = pbuf + (long)z * 8 * 16384 + rem;
    float s = 0.f;
    #pragma unroll
    for (int ns = 0; ns < 8; ++ns) s += p[ns * 16384];
    attnD[(long)z * 16384 + d * 128 + l] = f2b(s * iSs[b * 1024 + h * 128 + d]);
}

// ---------------------------------------------------------------------------
extern "C" void kernel_launch(void* const* d_in, const int* in_sizes, int n_in,
                              void* d_out, int out_size, void* d_ws, size_t ws_size,
                              hipStream_t stream) {
    const float* query = (const float*)d_in[0];
    const float* x     = (const float*)d_in[1];
    const float* cond  = (const float*)d_in[2];
    const float* smask = (const float*)d_in[3];
    const float* cmask = (const float*)d_in[4];
    const float* gx  = (const float*)d_in[5];
    const float* bx  = (const float*)d_in[6];
    const float* gc  = (const float*)d_in[7];
    const float* bc  = (const float*)d_in[8];
    const float* Wkc = (const float*)d_in[9];
    const float* bkc = (const float*)d_in[10];
    const float* Wvc = (const float*)d_in[11];
    const float* bvc = (const float*)d_in[12];
    const float* Wkx = (const float*)d_in[13];
    const float* bkx = (const float*)d_in[14];
    const float* Wvx = (const float*)d_in[15];
    const float* bvx = (const float*)d_in[16];
    const float* Wy  = (const float*)d_in[17];
    const float* by  = (const float*)d_in[18];

    // Workspace layout (bytes) — identical 'need' to the passing runs.
    size_t o_xn    = 0;                      // 33,554,432 (pbuf alias)
    size_t o_cn    = o_xn    + 33554432;     //  4,194,304 (partM/S alias later)
    size_t o_klog  = o_cn    + 4194304;      // 41,943,040 (Zt alias after attn)
    size_t o_vbuf  = o_klog  + 41943040;     // 41,943,040
    size_t o_qsm   = o_vbuf  + 41943040;     // 33,554,432
    size_t o_attnD = o_qsm   + 33554432;     //  2,097,152
    size_t o_partM = o_attnD + 2097152;      //    327,680 (unused now)
    size_t o_partS = o_partM + 327680;       //    327,680 (unused now)
    size_t o_Ms    = o_partS + 327680;       //     32,768
    size_t o_iSs   = o_Ms    + 32768;        //     32,768
    size_t o_wkc   = o_iSs   + 32768;        //  1,048,576  } weights contiguous
    size_t o_wvc   = o_wkc   + 1048576;      //  1,048,576  }
    size_t o_wkx   = o_wvc   + 1048576;      //  2,097,152  }
    size_t o_wvx   = o_wkx   + 2097152;      //  2,097,152  }
    size_t o_wy    = o_wvx   + 2097152;      //  2,097,152  }
    size_t need    = o_wy    + 2097152;      // = 166,395,904
    if (ws_size < need) return;  // clean no-op -> diagnosable absmax failure

    char* w = (char*)d_ws;
    short* xn    = (short*)(w + o_xn);
    short* cn    = (short*)(w + o_cn);
    short* klog  = (short*)(w + o_klog);
    short* vbuf  = (short*)(w + o_vbuf);
    short* qsm   = (short*)(w + o_qsm);
    short* attnD = (short*)(w + o_attnD);
    float* Ms    = (float*)(w + o_Ms);
    float* iSs   = (float*)(w + o_iSs);
    short* wkc   = (short*)(w + o_wkc);   // [wkc|wvc] = cat B for cond KV GEMM
    short* wkx   = (short*)(w + o_wkx);   // [wkx|wvx] = cat B for x KV GEMM
    short* wy    = (short*)(w + o_wy);
    float* pbuf  = (float*)xn;            // xn dead after KV GEMMs
    short* Zt    = klog;                  // klog dead after attn_part
    // kstats partials (8 b x 40 z x 1024 c f32 = 1,310,720 B each) live in the
    // cn region: cn (4 MB) is dead after the cond KV GEMM, before kstats1.
    float* partM = (float*)(w + o_cn);
    float* partS = (float*)(w + o_cn + 1310720);

    // Allow 128 KiB dynamic LDS for the 256^2 rings (host-side, capture-safe).
    static bool attr_set = false;
    if (!attr_set) {
        (void)hipFuncSetAttribute((const void*)gemm256<0>,
                                  hipFuncAttributeMaxDynamicSharedMemorySize, 131072);
        (void)hipFuncSetAttribute((const void*)gemm256<4>,
                                  hipFuncAttributeMaxDynamicSharedMemorySize, 131072);
        attr_set = true;
    }

    // Weight conversion f32 -> bf16 (single launch; dst region is contiguous)
    cvt_all<<<4096, 256, 0, stream>>>(Wkc, Wvc, Wkx, Wvx, Wy, wkc);

    ln_kernel<<<16384, 256, 0, stream>>>(x, gx, bx, xn, 1024);
    ln_kernel<<<4096, 256, 0, stream>>>(cond, gc, bc, cn, 512);
    qsoftmax_kernel<<<32768, 256, 0, stream>>>(query, qsm);

    // Fused k+v projection, x source: N=2048 (k|v), K=1024, z=8.
    // Split into two half-M launches (m rows 0-1023 / 1024-2047): identical
    // total work & rounds, drops max dispatch to ~60us so rocprof top-5
    // exposes the hidden non-GEMM dispatches.
    gemm256<0><<<dim3(8, 4, 8), 512, 131072, stream>>>(
        xn, 1024, 2097152L, wkx, 1024,
        klog + 512 * 1024, vbuf + 512 * 1024, 1024, 2621440L,
        1024, bkx, bvx, smask, 2048L);
    gemm256<0><<<dim3(8, 4, 8), 512, 131072, stream>>>(
        xn + 1048576, 1024, 2097152L, wkx, 1024,
        klog + 512 * 1024 + 1048576, vbuf + 512 * 1024 + 1048576, 1024, 2621440L,
        1024, bkx, bvx, smask + 1024, 2048L);
    // Fused k+v projection, cond source: N=2048, K=512, M=512/b, z=8 (128^2)
    gemm_bt<0><<<dim3(16, 4, 8), 256, 0, stream>>>(
        cn, 512, 262144L, wkc, 512,
        klog, vbuf, 1024, 2621440L,
        512, bkc, bvc, cmask, 512L);

    kstats1<<<dim3(4, 8, 40), 256, 0, stream>>>(klog, cmask, smask, partM, partS);
    kstats2<<<dim3(4, 8), 256, 0, stream>>>(partM, partS, Ms, iSs);

    // Split-K attention KV (pbuf overwrites xn region — xn dead by now)
    attn_part<<<dim3(8, 64), 256, 0, stream>>>(klog, vbuf, cmask, smask, Ms, pbuf);
    reduce_attn<<<4096, 256, 0, stream>>>(pbuf, iSs, attnD);

    // Zt[b][o][h*128+d] = sum_l Wy[o][h*128+l] * attnD[b,h][d][l]
    gemm_bt<2><<<dim3(1, 8, 64), 256, 0, stream>>>(
        wy, 1024, 0L, attnD, 128,
        Zt, nullptr, 1024, 0L,
        128, nullptr, nullptr, nullptr, 0L);
    // out[b] = qsm[b] @ Zt[b]^T + by   (f32 out, 256^2 4-buf ring, 1 blk/CU)
    gemm256<4><<<dim3(4, 8, 8), 512, 131072, stream>>>(
        qsm, 1024, 2097152L, Zt, 1024,
        d_out, nullptr, 1024, 2097152L,
        1024, by, nullptr, nullptr, 0L);
}